// Round 2
// baseline (19.834 us; speedup 1.0000x reference)
//
#include <hip/hip_runtime.h>

constexpr int NE = 8;       // N_ELEMENT
constexpr int NL = 32;      // N_LINES
constexpr int MB = 512;     // MINIBATCH
constexpr int SN = 1024;    // SAMPLE_N
constexpr float KS   = 0.01f / 1024.0f;  // SAMPLE_CM / SAMPLE_N
constexpr float I0   = 100000.0f;        // PROBE_I0
constexpr float OUTS = 0.05f;            // DET_SOLID_ANGLE_RATIO * SIGNAL_ATT

// One block per batch row b. 1024 threads (16 waves), 1 sample per thread.
// 512 blocks x 16 waves = 2 blocks/CU = 32 waves/CU (full wave occupancy).
__global__ __launch_bounds__(1024)
void ppm_kernel(const float* __restrict__ xp,   // [8][512][1024]
                const float* __restrict__ mu,   // [8]
                const float* __restrict__ fl,   // [32]
                const float* __restrict__ SA,   // [32][512*1024]
                float* __restrict__ out)        // [32*512 fl_signal | 512 trans]
{
    const int b    = blockIdx.x;
    const int t    = threadIdx.x;
    const int lane = t & 63;
    const int wv   = t >> 6;                    // 0..15

    __shared__ float s_wave[16];
    __shared__ float s_wx[NE][SN];              // weighted conc, 32 KB

    // ---- load xp sample t for all 8 elements (coalesced scalar loads) ----
    float x[NE];
    float a = 0.f;
    #pragma unroll
    for (int e = 0; e < NE; ++e) {
        x[e] = xp[(size_t)e * (MB * SN) + (size_t)b * SN + t];
        a = fmaf(mu[e], x[e], a);
    }

    // ---- wave-level inclusive scan (width 64) ----
    float incl = a;
    #pragma unroll
    for (int d = 1; d < 64; d <<= 1) {
        const float v = __shfl_up(incl, d, 64);
        if (lane >= d) incl += v;
    }
    if (lane == 63) s_wave[wv] = incl;
    __syncthreads();

    // cross-wave exclusive offset (16 wave totals, predicated sum)
    float woff = 0.f;
    #pragma unroll
    for (int w2 = 0; w2 < 16; ++w2) woff += (w2 < wv) ? s_wave[w2] : 0.f;
    const float pex = woff + (incl - a);        // block-level exclusive prefix
    const float w   = I0 * __expf(-KS * pex);   // attenuation weight for sample t

    // transmission_att_exponent[b] = KS * grand total
    if (t == 0) {
        float tot = 0.f;
        #pragma unroll
        for (int w2 = 0; w2 < 16; ++w2) tot += s_wave[w2];
        out[NL * MB + b] = KS * tot;
    }

    // ---- stage weighted conc in LDS ----
    #pragma unroll
    for (int e = 0; e < NE; ++e) s_wx[e][t] = w * x[e];
    __syncthreads();

    // ---- each wave owns 2 lines: l = wv and wv+16 ----
    #pragma unroll
    for (int li = 0; li < 2; ++li) {
        const int l = wv + 16 * li;
        const int e = l >> 2;
        const float4* sa4 = reinterpret_cast<const float4*>(
            SA + (size_t)l * (size_t)(MB * SN) + (size_t)b * SN);
        const float4* wx4 = reinterpret_cast<const float4*>(&s_wx[e][0]);
        float acc = 0.f;
        #pragma unroll
        for (int j = 0; j < 4; ++j) {
            const int idx = lane + 64 * j;      // contiguous float4 per wave
            const float4 sa = sa4[idx];
            const float4 wx = wx4[idx];
            acc += wx.x * sa.x + wx.y * sa.y + wx.z * sa.z + wx.w * sa.w;
        }
        // wave shuffle reduction
        #pragma unroll
        for (int d = 32; d >= 1; d >>= 1) acc += __shfl_down(acc, d, 64);
        if (lane == 0) out[l * MB + b] = OUTS * fl[l] * acc;
    }
}

extern "C" void kernel_launch(void* const* d_in, const int* in_sizes, int n_in,
                              void* d_out, int out_size, void* d_ws, size_t ws_size,
                              hipStream_t stream) {
    const float* xp = (const float*)d_in[0];
    const float* mu = (const float*)d_in[1];
    const float* fl = (const float*)d_in[2];
    const float* SA = (const float*)d_in[3];
    float* out = (float*)d_out;
    ppm_kernel<<<MB, 1024, 0, stream>>>(xp, mu, fl, SA, out);
}